// Round 1
// baseline (182.401 us; speedup 1.0000x reference)
//
#include <hip/hip_runtime.h>
#include <hip/hip_bf16.h>
#include <math.h>

// Problem constants
#define BB 2
#define HH 64
#define WW 64
#define CC 192
#define NH 6
#define HD 32
#define KS 7
#define KK 49
#define NPIX (BB * HH * WW)          // 8192
#define SCALE 0.17677669529663687f   // 1/sqrt(32)

// ---------------------------------------------------------------------------
// Generic tiled fp32 GEMM:  C[M,N] = A[M,K] * B[N,K]^T   (both row-major)
// TILE 64x64, TK=16, 256 threads, 4x4 micro-tile per thread.
// Requires M%64==0, N%64==0, K%16==0 (true for all our shapes).
// ---------------------------------------------------------------------------
#define TM 64
#define TN 64
#define TKC 16

__global__ __launch_bounds__(256) void gemm_abt(const float* __restrict__ A,
                                                const float* __restrict__ Bw,
                                                float* __restrict__ Cm,
                                                int M, int N, int Kd) {
    __shared__ float As[TKC][TM + 4];
    __shared__ float Bs[TKC][TN + 4];

    const int t  = threadIdx.x;
    const int tx = t & 15;    // 0..15  -> 4 output cols each
    const int ty = t >> 4;    // 0..15  -> 4 output rows each
    const int row0 = blockIdx.x * TM;
    const int col0 = blockIdx.y * TN;

    // loader mapping: each thread loads one float4 (4 consecutive k) of A and B
    const int lm = t >> 2;          // 0..63 (tile row)
    const int lk = (t & 3) * 4;     // 0,4,8,12 (k offset)

    float acc[4][4];
#pragma unroll
    for (int i = 0; i < 4; ++i)
#pragma unroll
        for (int j = 0; j < 4; ++j) acc[i][j] = 0.f;

    for (int k0 = 0; k0 < Kd; k0 += TKC) {
        float4 av = *(const float4*)(A  + (size_t)(row0 + lm) * Kd + k0 + lk);
        float4 bv = *(const float4*)(Bw + (size_t)(col0 + lm) * Kd + k0 + lk);
        __syncthreads();   // protect previous iteration's LDS reads
        As[lk + 0][lm] = av.x; As[lk + 1][lm] = av.y;
        As[lk + 2][lm] = av.z; As[lk + 3][lm] = av.w;
        Bs[lk + 0][lm] = bv.x; Bs[lk + 1][lm] = bv.y;
        Bs[lk + 2][lm] = bv.z; Bs[lk + 3][lm] = bv.w;
        __syncthreads();

#pragma unroll
        for (int kk = 0; kk < TKC; ++kk) {
            float4 a4 = *(const float4*)&As[kk][ty * 4];
            float4 b4 = *(const float4*)&Bs[kk][tx * 4];
            float ar[4] = {a4.x, a4.y, a4.z, a4.w};
            float br[4] = {b4.x, b4.y, b4.z, b4.w};
#pragma unroll
            for (int i = 0; i < 4; ++i)
#pragma unroll
                for (int j = 0; j < 4; ++j)
                    acc[i][j] = fmaf(ar[i], br[j], acc[i][j]);
        }
    }

#pragma unroll
    for (int i = 0; i < 4; ++i) {
        float4 o = make_float4(acc[i][0], acc[i][1], acc[i][2], acc[i][3]);
        *(float4*)(Cm + (size_t)(row0 + ty * 4 + i) * N + col0 + tx * 4) = o;
    }
}

// ---------------------------------------------------------------------------
// Fused neighborhood attention with online softmax.
// One thread per (b, head, i, j). Block = 64 threads = one image row for one
// (b, head). Grid = B*NH*H = 768 blocks.
// qkv layout: [b, i, j, 576] where 576 = {q:0, k:192, v:384} + head*32 + d
// out layout: [b, i, j, 192] (c = head*32 + d)
// ---------------------------------------------------------------------------
__global__ __launch_bounds__(64) void natten_fused(const float* __restrict__ qkv,
                                                   const float* __restrict__ rpb,
                                                   const float* __restrict__ temperature,
                                                   float* __restrict__ out) {
    const int j    = threadIdx.x;               // 0..63
    const int i    = blockIdx.x & 63;           // 0..63
    const int head = (blockIdx.x >> 6) % NH;    // 0..5
    const int b    = blockIdx.x / (64 * NH);    // 0..1

    __shared__ float srpb[13 * 13];
    for (int idx = j; idx < 169; idx += 64) srpb[idx] = rpb[head * 169 + idx];
    __syncthreads();

    const float temp = temperature[head];

    const size_t pix = (size_t)b * 4096 + i * 64 + j;
    const float* qp = qkv + pix * 576 + head * HD;   // q block

    float q[HD];
#pragma unroll
    for (int d4 = 0; d4 < 8; ++d4) {
        float4 v4 = *(const float4*)(qp + d4 * 4);
        q[d4 * 4 + 0] = v4.x * SCALE;
        q[d4 * 4 + 1] = v4.y * SCALE;
        q[d4 * 4 + 2] = v4.z * SCALE;
        q[d4 * 4 + 3] = v4.w * SCALE;
    }

    float m = -1e30f, l = 0.f;
    float acc[HD];
#pragma unroll
    for (int d = 0; d < HD; ++d) acc[d] = 0.f;

    const int si = min(max(i - 3, 0), HH - KS);  // clamped window start row
    const int sj = min(max(j - 3, 0), WW - KS);  // clamped window start col

    for (int ki = 0; ki < KS; ++ki) {
        const int ni = si + ki;
        const int ri = ni - i + 6;                    // 0..12
        const float* rowb = &srpb[ri * 13];
        const size_t rowbase = ((size_t)b * 4096 + (size_t)ni * 64) * 576;
        for (int kj = 0; kj < KS; ++kj) {
            const int nj = sj + kj;
            const float* kp = qkv + rowbase + (size_t)nj * 576 + CC + head * HD;

            float dot = 0.f;
#pragma unroll
            for (int d4 = 0; d4 < 8; ++d4) {
                float4 k4 = *(const float4*)(kp + d4 * 4);
                dot = fmaf(q[d4 * 4 + 0], k4.x, dot);
                dot = fmaf(q[d4 * 4 + 1], k4.y, dot);
                dot = fmaf(q[d4 * 4 + 2], k4.z, dot);
                dot = fmaf(q[d4 * 4 + 3], k4.w, dot);
            }
            const float logit = (dot + rowb[nj - j + 6]) * temp;

            const float mn    = fmaxf(m, logit);
            const float alpha = __expf(m - mn);
            const float p     = __expf(logit - mn);
            l = l * alpha + p;

            const float* vp = kp + CC;   // v block
#pragma unroll
            for (int d4 = 0; d4 < 8; ++d4) {
                float4 v4 = *(const float4*)(vp + d4 * 4);
                acc[d4 * 4 + 0] = fmaf(acc[d4 * 4 + 0], alpha, p * v4.x);
                acc[d4 * 4 + 1] = fmaf(acc[d4 * 4 + 1], alpha, p * v4.y);
                acc[d4 * 4 + 2] = fmaf(acc[d4 * 4 + 2], alpha, p * v4.z);
                acc[d4 * 4 + 3] = fmaf(acc[d4 * 4 + 3], alpha, p * v4.w);
            }
            m = mn;
        }
    }

    const float inv = 1.f / l;
    float* op = out + pix * CC + head * HD;
#pragma unroll
    for (int d4 = 0; d4 < 8; ++d4) {
        float4 o = make_float4(acc[d4 * 4 + 0] * inv, acc[d4 * 4 + 1] * inv,
                               acc[d4 * 4 + 2] * inv, acc[d4 * 4 + 3] * inv);
        *(float4*)(op + d4 * 4) = o;
    }
}

// ---------------------------------------------------------------------------
extern "C" void kernel_launch(void* const* d_in, const int* in_sizes, int n_in,
                              void* d_out, int out_size, void* d_ws, size_t ws_size,
                              hipStream_t stream) {
    const float* x           = (const float*)d_in[0];  // (2,64,64,192)
    const float* w_qkv       = (const float*)d_in[1];  // (576,192)
    const float* rpb         = (const float*)d_in[2];  // (6,13,13)
    const float* temperature = (const float*)d_in[3];  // (6,)
    const float* w_proj      = (const float*)d_in[4];  // (192,192)
    float* out = (float*)d_out;                        // (2,64,64,192)

    float* qkv      = (float*)d_ws;                    // 8192*576 floats
    float* attn_out = qkv + (size_t)NPIX * 3 * CC;     // 8192*192 floats

    // 1) qkv = x @ w_qkv^T   (M=8192, N=576, K=192)
    gemm_abt<<<dim3(NPIX / TM, (3 * CC) / TN), 256, 0, stream>>>(
        x, w_qkv, qkv, NPIX, 3 * CC, CC);

    // 2) fused neighborhood attention
    natten_fused<<<dim3(BB * NH * HH), 64, 0, stream>>>(
        qkv, rpb, temperature, attn_out);

    // 3) out = attn_out @ w_proj^T  (M=8192, N=192, K=192)
    gemm_abt<<<dim3(NPIX / TM, CC / TN), 256, 0, stream>>>(
        attn_out, w_proj, out, NPIX, CC, CC);
}

// Round 2
// 138.586 us; speedup vs baseline: 1.3162x; 1.3162x over previous
//
#include <hip/hip_runtime.h>
#include <hip/hip_bf16.h>
#include <math.h>

// Problem constants
#define BB 2
#define HH 64
#define WW 64
#define CC 192
#define NH 6
#define HD 32
#define KS 7
#define NPIX (BB * HH * WW)          // 8192
#define SCALE 0.17677669529663687f   // 1/sqrt(32)

// ---------------------------------------------------------------------------
// Generic tiled fp32 GEMM:  C[M,N] = A[M,K] * B[N,K]^T   (both row-major)
// ---------------------------------------------------------------------------
#define TM 64
#define TN 64
#define TKC 16

__global__ __launch_bounds__(256) void gemm_abt(const float* __restrict__ A,
                                                const float* __restrict__ Bw,
                                                float* __restrict__ Cm,
                                                int M, int N, int Kd) {
    __shared__ float As[TKC][TM + 4];
    __shared__ float Bs[TKC][TN + 4];

    const int t  = threadIdx.x;
    const int tx = t & 15;
    const int ty = t >> 4;
    const int row0 = blockIdx.x * TM;
    const int col0 = blockIdx.y * TN;

    const int lm = t >> 2;
    const int lk = (t & 3) * 4;

    float acc[4][4];
#pragma unroll
    for (int i = 0; i < 4; ++i)
#pragma unroll
        for (int j = 0; j < 4; ++j) acc[i][j] = 0.f;

    for (int k0 = 0; k0 < Kd; k0 += TKC) {
        float4 av = *(const float4*)(A  + (size_t)(row0 + lm) * Kd + k0 + lk);
        float4 bv = *(const float4*)(Bw + (size_t)(col0 + lm) * Kd + k0 + lk);
        __syncthreads();
        As[lk + 0][lm] = av.x; As[lk + 1][lm] = av.y;
        As[lk + 2][lm] = av.z; As[lk + 3][lm] = av.w;
        Bs[lk + 0][lm] = bv.x; Bs[lk + 1][lm] = bv.y;
        Bs[lk + 2][lm] = bv.z; Bs[lk + 3][lm] = bv.w;
        __syncthreads();

#pragma unroll
        for (int kk = 0; kk < TKC; ++kk) {
            float4 a4 = *(const float4*)&As[kk][ty * 4];
            float4 b4 = *(const float4*)&Bs[kk][tx * 4];
            float ar[4] = {a4.x, a4.y, a4.z, a4.w};
            float br[4] = {b4.x, b4.y, b4.z, b4.w};
#pragma unroll
            for (int i = 0; i < 4; ++i)
#pragma unroll
                for (int j = 0; j < 4; ++j)
                    acc[i][j] = fmaf(ar[i], br[j], acc[i][j]);
        }
    }

#pragma unroll
    for (int i = 0; i < 4; ++i) {
        float4 o = make_float4(acc[i][0], acc[i][1], acc[i][2], acc[i][3]);
        *(float4*)(Cm + (size_t)(row0 + ty * 4 + i) * N + col0 + tx * 4) = o;
    }
}

// ---------------------------------------------------------------------------
// natten_v2: block = (b, head, qrow), 256 threads = 4 waves.
// Wave w stages window rows {2w, 2w+1} (wave 3: row 6 only) into private LDS
// (k fp32 stride-33 dwords, v bf16-packed stride-17 u32 — both co-prime with
// 32 banks -> <=2 lanes/bank, conflict-free). Each wave runs online softmax
// for all 64 pixels of the query row over its neighbor subset; partials are
// merged through an LDS overlay aliased onto each wave's own staging region.
// ---------------------------------------------------------------------------
#define STRK 33            // k row stride in dwords
#define STRV 17            // v row stride in u32 (2 bf16 each)
#define VOFF 2112          // v offset inside a wave region (dwords) = 64*33
#define REGDW 3200         // region dwords: 2112 (k) + 1088 (v)
#define PSTR 34            // partial overlay stride (32 acc + m + l)

__device__ __forceinline__ unsigned bf16r(float x) {
    unsigned u = __float_as_uint(x);
    return (u + 0x7fffu + ((u >> 16) & 1u)) >> 16;   // RNE
}

__global__ __launch_bounds__(256, 3) void natten_v2(const float* __restrict__ qkv,
                                                    const float* __restrict__ rpb,
                                                    const float* __restrict__ temperature,
                                                    float* __restrict__ out) {
    const int tid  = threadIdx.x;
    const int w    = tid >> 6;        // wave 0..3
    const int j    = tid & 63;        // pixel column
    const int i    = blockIdx.x & 63;               // query row
    const int head = (blockIdx.x >> 6) % NH;
    const int b    = blockIdx.x / (64 * NH);

    __shared__ float region[4][REGDW];
    __shared__ float srpb[169];
    if (tid < 169) srpb[tid] = rpb[head * 169 + tid];

    const float temp = temperature[head];
    const size_t pix = (size_t)b * 4096 + i * 64 + j;
    const float* qp = qkv + pix * 576 + head * HD;

    float q[HD];
#pragma unroll
    for (int d4 = 0; d4 < 8; ++d4) {
        float4 f = *(const float4*)(qp + d4 * 4);
        q[d4 * 4 + 0] = f.x * SCALE; q[d4 * 4 + 1] = f.y * SCALE;
        q[d4 * 4 + 2] = f.z * SCALE; q[d4 * 4 + 3] = f.w * SCALE;
    }

    __syncthreads();   // srpb ready

    const int si = min(max(i - 3, 0), HH - KS);
    const int sj = min(max(j - 3, 0), WW - KS);

    float m = -1e30f, l = 0.f;
    float acc[HD];
#pragma unroll
    for (int d = 0; d < HD; ++d) acc[d] = 0.f;

    float*    kreg = region[w];
    unsigned* vreg = (unsigned*)(region[w] + VOFF);

    const int nrows = (w < 3) ? 2 : 1;
    for (int t = 0; t < nrows; ++t) {
        const int ki = 2 * w + t;
        const int ni = si + ki;

        // ---- stage k (fp32) + v (bf16) for row ni, this head ----
        const float* rowk = qkv + ((size_t)b * 4096 + (size_t)ni * 64) * 576 + CC + head * HD;
#pragma unroll
        for (int it = 0; it < 8; ++it) {
            const int idx = j + (it << 6);       // 0..511
            const int px = idx >> 3, d4 = idx & 7;
            const float* src = rowk + px * 576 + d4 * 4;
            float4 kf = *(const float4*)src;
            float4 vf = *(const float4*)(src + CC);
            float* kd = kreg + px * STRK + d4 * 4;
            kd[0] = kf.x; kd[1] = kf.y; kd[2] = kf.z; kd[3] = kf.w;
            unsigned* vd = vreg + px * STRV + d4 * 2;
            vd[0] = bf16r(vf.x) | (bf16r(vf.y) << 16);
            vd[1] = bf16r(vf.z) | (bf16r(vf.w) << 16);
        }
        // wave-synchronous: compiler orders ds_write -> ds_read via lgkmcnt

        const float* rb = srpb + (ni - i + 6) * 13;
#pragma unroll
        for (int kj = 0; kj < 7; ++kj) {
            const int nj = sj + kj;
            const float* kk = kreg + nj * STRK;
            float dot = 0.f;
#pragma unroll
            for (int d = 0; d < HD; ++d) dot = fmaf(q[d], kk[d], dot);
            const float logit = (dot + rb[nj - j + 6]) * temp;

            const float mn    = fmaxf(m, logit);
            const float alpha = __expf(m - mn);
            const float p     = __expf(logit - mn);
            l = l * alpha + p;
            m = mn;

            const unsigned* vv = vreg + nj * STRV;
#pragma unroll
            for (int c = 0; c < 16; ++c) {
                const unsigned u = vv[c];
                const float lo = __uint_as_float(u << 16);
                const float hi = __uint_as_float(u & 0xffff0000u);
                acc[2 * c + 0] = fmaf(acc[2 * c + 0], alpha, p * lo);
                acc[2 * c + 1] = fmaf(acc[2 * c + 1], alpha, p * hi);
            }
        }
    }

    // ---- merge the 4 wave partials (overlay aliases own staging region) ----
    if (w > 0) {
        float* pp = region[w] + j * PSTR;
#pragma unroll
        for (int d = 0; d < HD; ++d) pp[d] = acc[d];
        pp[32] = m; pp[33] = l;
    }
    __syncthreads();
    if (w == 0) {
#pragma unroll
        for (int ww = 1; ww < 4; ++ww) {
            const float* pp = region[ww] + j * PSTR;
            const float m2 = pp[32], l2 = pp[33];
            const float mn = fmaxf(m, m2);
            const float a1 = __expf(m - mn), a2 = __expf(m2 - mn);
            l = l * a1 + l2 * a2;
#pragma unroll
            for (int d = 0; d < HD; ++d) acc[d] = acc[d] * a1 + pp[d] * a2;
            m = mn;
        }
        const float inv = 1.f / l;
        float* op = out + pix * CC + head * HD;
#pragma unroll
        for (int d4 = 0; d4 < 8; ++d4) {
            float4 o = make_float4(acc[d4 * 4 + 0] * inv, acc[d4 * 4 + 1] * inv,
                                   acc[d4 * 4 + 2] * inv, acc[d4 * 4 + 3] * inv);
            *(float4*)(op + d4 * 4) = o;
        }
    }
}

// ---------------------------------------------------------------------------
extern "C" void kernel_launch(void* const* d_in, const int* in_sizes, int n_in,
                              void* d_out, int out_size, void* d_ws, size_t ws_size,
                              hipStream_t stream) {
    const float* x           = (const float*)d_in[0];
    const float* w_qkv       = (const float*)d_in[1];
    const float* rpb         = (const float*)d_in[2];
    const float* temperature = (const float*)d_in[3];
    const float* w_proj      = (const float*)d_in[4];
    float* out = (float*)d_out;

    float* qkv      = (float*)d_ws;
    float* attn_out = qkv + (size_t)NPIX * 3 * CC;

    gemm_abt<<<dim3(NPIX / TM, (3 * CC) / TN), 256, 0, stream>>>(
        x, w_qkv, qkv, NPIX, 3 * CC, CC);

    natten_v2<<<dim3(BB * NH * HH), 256, 0, stream>>>(
        qkv, rpb, temperature, attn_out);

    gemm_abt<<<dim3(NPIX / TM, CC / TN), 256, 0, stream>>>(
        attn_out, w_proj, out, NPIX, CC, CC);
}

// Round 3
// 111.431 us; speedup vs baseline: 1.6369x; 1.2437x over previous
//
#include <hip/hip_runtime.h>
#include <hip/hip_bf16.h>
#include <math.h>

// Problem constants
#define BB 2
#define HH 64
#define WW 64
#define CC 192
#define NH 6
#define HD 32
#define KS 7
#define NPIX (BB * HH * WW)          // 8192
#define SCALE 0.17677669529663687f   // 1/sqrt(32)
#define GK 192                       // K dim for both GEMMs

typedef __attribute__((ext_vector_type(8))) _Float16 f16x8;
typedef __attribute__((ext_vector_type(4))) float    f32x4;

// ---------------------------------------------------------------------------
// MFMA fp16 GEMM:  C[M,N] = A[M,GK] * B[N,GK]^T  (fp32 in/out, fp16 compute)
// 64x64 tile, 256 threads = 4 waves (2x2), each wave 2x2 MFMA 16x16 tiles.
// Full K=192 staged once -> single barrier per block.
// LDS row stride 200 halves (100 dwords % 32 = 4 -> 2-way bank alias, free).
// ---------------------------------------------------------------------------
#define LDA 200

__global__ __launch_bounds__(256) void gemm_mfma(const float* __restrict__ A,
                                                 const float* __restrict__ Bw,
                                                 float* __restrict__ Cm,
                                                 int M, int N) {
    __shared__ _Float16 As[64 * LDA];
    __shared__ _Float16 Bs[64 * LDA];

    const int t    = threadIdx.x;
    const int row0 = blockIdx.x * 64;
    const int col0 = blockIdx.y * 64;

    // ---- stage A,B tiles: 64 rows x 192 fp32 -> fp16, 16B LDS writes ----
#pragma unroll
    for (int it = 0; it < 6; ++it) {
        const int idx = t + it * 256;          // 0..1535 half8-chunks
        const int r   = idx / 24;
        const int c8  = (idx % 24) * 8;
        const float* pa = A  + (size_t)(row0 + r) * GK + c8;
        const float* pb = Bw + (size_t)(col0 + r) * GK + c8;
        float4 a0 = *(const float4*)pa;
        float4 a1 = *(const float4*)(pa + 4);
        float4 b0 = *(const float4*)pb;
        float4 b1 = *(const float4*)(pb + 4);
        f16x8 ha, hb;
        ha[0] = (_Float16)a0.x; ha[1] = (_Float16)a0.y;
        ha[2] = (_Float16)a0.z; ha[3] = (_Float16)a0.w;
        ha[4] = (_Float16)a1.x; ha[5] = (_Float16)a1.y;
        ha[6] = (_Float16)a1.z; ha[7] = (_Float16)a1.w;
        hb[0] = (_Float16)b0.x; hb[1] = (_Float16)b0.y;
        hb[2] = (_Float16)b0.z; hb[3] = (_Float16)b0.w;
        hb[4] = (_Float16)b1.x; hb[5] = (_Float16)b1.y;
        hb[6] = (_Float16)b1.z; hb[7] = (_Float16)b1.w;
        *(f16x8*)&As[r * LDA + c8] = ha;
        *(f16x8*)&Bs[r * LDA + c8] = hb;
    }
    __syncthreads();

    const int wave = t >> 6;
    const int wr   = wave >> 1;       // 0..1 -> row half
    const int wc   = wave & 1;        // 0..1 -> col half
    const int lane = t & 63;
    const int ln   = lane & 15;
    const int quad = lane >> 4;

    f32x4 acc[2][2] = {};

#pragma unroll
    for (int ks = 0; ks < 6; ++ks) {
        const int k0 = ks * 32 + quad * 8;
        f16x8 af[2], bf[2];
#pragma unroll
        for (int mi = 0; mi < 2; ++mi)
            af[mi] = *(const f16x8*)&As[(wr * 32 + mi * 16 + ln) * LDA + k0];
#pragma unroll
        for (int ni = 0; ni < 2; ++ni)
            bf[ni] = *(const f16x8*)&Bs[(wc * 32 + ni * 16 + ln) * LDA + k0];
#pragma unroll
        for (int mi = 0; mi < 2; ++mi)
#pragma unroll
            for (int ni = 0; ni < 2; ++ni)
                acc[mi][ni] = __builtin_amdgcn_mfma_f32_16x16x32_f16(
                    af[mi], bf[ni], acc[mi][ni], 0, 0, 0);
    }

    // C/D layout: col = lane&15, row = quad*4 + reg
#pragma unroll
    for (int mi = 0; mi < 2; ++mi)
#pragma unroll
        for (int ni = 0; ni < 2; ++ni) {
            const int col = col0 + wc * 32 + ni * 16 + ln;
#pragma unroll
            for (int r = 0; r < 4; ++r) {
                const int row = row0 + wr * 32 + mi * 16 + quad * 4 + r;
                Cm[(size_t)row * N + col] = acc[mi][ni][r];
            }
        }
}

// ---------------------------------------------------------------------------
// natten_v2 (unchanged from R1): block = (b, head, qrow), 256 threads.
// ---------------------------------------------------------------------------
#define STRK 33
#define STRV 17
#define VOFF 2112
#define REGDW 3200
#define PSTR 34

__device__ __forceinline__ unsigned bf16r(float x) {
    unsigned u = __float_as_uint(x);
    return (u + 0x7fffu + ((u >> 16) & 1u)) >> 16;   // RNE
}

__global__ __launch_bounds__(256, 3) void natten_v2(const float* __restrict__ qkv,
                                                    const float* __restrict__ rpb,
                                                    const float* __restrict__ temperature,
                                                    float* __restrict__ out) {
    const int tid  = threadIdx.x;
    const int w    = tid >> 6;
    const int j    = tid & 63;
    const int i    = blockIdx.x & 63;
    const int head = (blockIdx.x >> 6) % NH;
    const int b    = blockIdx.x / (64 * NH);

    __shared__ float region[4][REGDW];
    __shared__ float srpb[169];
    if (tid < 169) srpb[tid] = rpb[head * 169 + tid];

    const float temp = temperature[head];
    const size_t pix = (size_t)b * 4096 + i * 64 + j;
    const float* qp = qkv + pix * 576 + head * HD;

    float q[HD];
#pragma unroll
    for (int d4 = 0; d4 < 8; ++d4) {
        float4 f = *(const float4*)(qp + d4 * 4);
        q[d4 * 4 + 0] = f.x * SCALE; q[d4 * 4 + 1] = f.y * SCALE;
        q[d4 * 4 + 2] = f.z * SCALE; q[d4 * 4 + 3] = f.w * SCALE;
    }

    __syncthreads();

    const int si = min(max(i - 3, 0), HH - KS);
    const int sj = min(max(j - 3, 0), WW - KS);

    float m = -1e30f, l = 0.f;
    float acc[HD];
#pragma unroll
    for (int d = 0; d < HD; ++d) acc[d] = 0.f;

    float*    kreg = region[w];
    unsigned* vreg = (unsigned*)(region[w] + VOFF);

    const int nrows = (w < 3) ? 2 : 1;
    for (int t = 0; t < nrows; ++t) {
        const int ki = 2 * w + t;
        const int ni = si + ki;

        const float* rowk = qkv + ((size_t)b * 4096 + (size_t)ni * 64) * 576 + CC + head * HD;
#pragma unroll
        for (int it = 0; it < 8; ++it) {
            const int idx = j + (it << 6);
            const int px = idx >> 3, d4 = idx & 7;
            const float* src = rowk + px * 576 + d4 * 4;
            float4 kf = *(const float4*)src;
            float4 vf = *(const float4*)(src + CC);
            float* kd = kreg + px * STRK + d4 * 4;
            kd[0] = kf.x; kd[1] = kf.y; kd[2] = kf.z; kd[3] = kf.w;
            unsigned* vd = vreg + px * STRV + d4 * 2;
            vd[0] = bf16r(vf.x) | (bf16r(vf.y) << 16);
            vd[1] = bf16r(vf.z) | (bf16r(vf.w) << 16);
        }

        const float* rb = srpb + (ni - i + 6) * 13;
#pragma unroll
        for (int kj = 0; kj < 7; ++kj) {
            const int nj = sj + kj;
            const float* kk = kreg + nj * STRK;
            float dot = 0.f;
#pragma unroll
            for (int d = 0; d < HD; ++d) dot = fmaf(q[d], kk[d], dot);
            const float logit = (dot + rb[nj - j + 6]) * temp;

            const float mn    = fmaxf(m, logit);
            const float alpha = __expf(m - mn);
            const float p     = __expf(logit - mn);
            l = l * alpha + p;
            m = mn;

            const unsigned* vv = vreg + nj * STRV;
#pragma unroll
            for (int c = 0; c < 16; ++c) {
                const unsigned u = vv[c];
                const float lo = __uint_as_float(u << 16);
                const float hi = __uint_as_float(u & 0xffff0000u);
                acc[2 * c + 0] = fmaf(acc[2 * c + 0], alpha, p * lo);
                acc[2 * c + 1] = fmaf(acc[2 * c + 1], alpha, p * hi);
            }
        }
    }

    if (w > 0) {
        float* pp = region[w] + j * PSTR;
#pragma unroll
        for (int d = 0; d < HD; ++d) pp[d] = acc[d];
        pp[32] = m; pp[33] = l;
    }
    __syncthreads();
    if (w == 0) {
#pragma unroll
        for (int ww = 1; ww < 4; ++ww) {
            const float* pp = region[ww] + j * PSTR;
            const float m2 = pp[32], l2 = pp[33];
            const float mn = fmaxf(m, m2);
            const float a1 = __expf(m - mn), a2 = __expf(m2 - mn);
            l = l * a1 + l2 * a2;
#pragma unroll
            for (int d = 0; d < HD; ++d) acc[d] = acc[d] * a1 + pp[d] * a2;
            m = mn;
        }
        const float inv = 1.f / l;
        float* op = out + pix * CC + head * HD;
#pragma unroll
        for (int d4 = 0; d4 < 8; ++d4) {
            float4 o = make_float4(acc[d4 * 4 + 0] * inv, acc[d4 * 4 + 1] * inv,
                                   acc[d4 * 4 + 2] * inv, acc[d4 * 4 + 3] * inv);
            *(float4*)(op + d4 * 4) = o;
        }
    }
}

// ---------------------------------------------------------------------------
extern "C" void kernel_launch(void* const* d_in, const int* in_sizes, int n_in,
                              void* d_out, int out_size, void* d_ws, size_t ws_size,
                              hipStream_t stream) {
    const float* x           = (const float*)d_in[0];
    const float* w_qkv       = (const float*)d_in[1];
    const float* rpb         = (const float*)d_in[2];
    const float* temperature = (const float*)d_in[3];
    const float* w_proj      = (const float*)d_in[4];
    float* out = (float*)d_out;

    float* qkv      = (float*)d_ws;
    float* attn_out = qkv + (size_t)NPIX * 3 * CC;

    // 1) qkv = x @ w_qkv^T   (M=8192, N=576, K=192)  fp16 MFMA
    gemm_mfma<<<dim3(NPIX / 64, (3 * CC) / 64), 256, 0, stream>>>(
        x, w_qkv, qkv, NPIX, 3 * CC);

    // 2) fused neighborhood attention
    natten_v2<<<dim3(BB * NH * HH), 256, 0, stream>>>(
        qkv, rpb, temperature, attn_out);

    // 3) out = attn_out @ w_proj^T  (M=8192, N=192, K=192)  fp16 MFMA
    gemm_mfma<<<dim3(NPIX / 64, CC / 64), 256, 0, stream>>>(
        attn_out, w_proj, out, NPIX, CC);
}